// Round 1
// baseline (80.063 us; speedup 1.0000x reference)
//
#include <hip/hip_runtime.h>

#define EPS 1e-8f

constexpr int NROWS = 1024;  // rows of x and of y
constexpr int K     = 256;   // feature dim
constexpr int TM    = 64;    // output tile rows per block (x rows)
constexpr int TN    = 64;    // output tile cols per block (y rows)
constexpr int KC    = 64;    // k-chunk staged in LDS
constexpr int PITCH = KC + 4; // 68 floats: breaks 16-way bank conflict, keeps 16B align

// Kernel A: row sums of x (rows 0..1023) and y (rows 1024..2047) into sums[2048].
// One wave per row: 64 lanes x float4 = 256 floats, shuffle-reduce.
__global__ __launch_bounds__(256) void rowsum_kernel(const float* __restrict__ x,
                                                     const float* __restrict__ y,
                                                     float* __restrict__ sums) {
    const int wave = threadIdx.x >> 6;   // 0..3
    const int lane = threadIdx.x & 63;
    const int row  = blockIdx.x * 4 + wave;   // 0..2047
    const float* src = (row < NROWS) ? (x + (size_t)row * K)
                                     : (y + (size_t)(row - NROWS) * K);
    float4 v = ((const float4*)src)[lane];
    float s = v.x + v.y + v.z + v.w;
    #pragma unroll
    for (int off = 32; off > 0; off >>= 1) s += __shfl_down(s, off);
    if (lane == 0) sums[row] = s;
}

// Kernel B: 64x64 output tile per block, 4x4 micro-tile per thread.
// num = sum(min); den = Sx + Sy - num + EPS.
__global__ __launch_bounds__(256) void ruzicka_kernel(const float* __restrict__ x,
                                                      const float* __restrict__ y,
                                                      const float* __restrict__ sums,
                                                      float* __restrict__ out) {
    __shared__ float xs[TM][PITCH];
    __shared__ float ys[TN][PITCH];

    const int tid = threadIdx.x;
    const int tx  = tid & 15;   // 0..15 -> 4-col group
    const int ty  = tid >> 4;   // 0..15 -> 4-row group
    const int rowBase = blockIdx.y * TM;   // x rows (output rows)
    const int colBase = blockIdx.x * TN;   // y rows (output cols)

    float num[4][4];
    #pragma unroll
    for (int r = 0; r < 4; ++r)
        #pragma unroll
        for (int c = 0; c < 4; ++c) num[r][c] = 0.0f;

    const int ldcol = (tid & 15) * 4;  // float4 col offset within chunk: 0..60
    const int ldrow = tid >> 4;        // 0..15; 4 passes cover 64 rows

    for (int kc = 0; kc < K; kc += KC) {
        #pragma unroll
        for (int p = 0; p < 4; ++p) {
            const int r = ldrow + 16 * p;
            const float4 xv = *(const float4*)&x[(size_t)(rowBase + r) * K + kc + ldcol];
            const float4 yv = *(const float4*)&y[(size_t)(colBase + r) * K + kc + ldcol];
            *(float4*)&xs[r][ldcol] = xv;
            *(float4*)&ys[r][ldcol] = yv;
        }
        __syncthreads();

        #pragma unroll 4
        for (int kk = 0; kk < KC; kk += 4) {
            float4 a[4], b[4];
            #pragma unroll
            for (int r = 0; r < 4; ++r) a[r] = *(const float4*)&xs[ty * 4 + r][kk];
            #pragma unroll
            for (int c = 0; c < 4; ++c) b[c] = *(const float4*)&ys[tx * 4 + c][kk];
            #pragma unroll
            for (int r = 0; r < 4; ++r)
                #pragma unroll
                for (int c = 0; c < 4; ++c) {
                    const float m0 = fminf(a[r].x, b[c].x);
                    const float m1 = fminf(a[r].y, b[c].y);
                    const float m2 = fminf(a[r].z, b[c].z);
                    const float m3 = fminf(a[r].w, b[c].w);
                    num[r][c] += (m0 + m1) + (m2 + m3);
                }
        }
        __syncthreads();
    }

    // Epilogue: den = Sx + Sy - num + EPS
    float sx[4], sy[4];
    #pragma unroll
    for (int r = 0; r < 4; ++r) sx[r] = sums[rowBase + ty * 4 + r];
    #pragma unroll
    for (int c = 0; c < 4; ++c) sy[c] = sums[NROWS + colBase + tx * 4 + c];

    #pragma unroll
    for (int r = 0; r < 4; ++r) {
        const int row = rowBase + ty * 4 + r;
        float4 o;
        float* op = &o.x;
        #pragma unroll
        for (int c = 0; c < 4; ++c) {
            const float n = num[r][c];
            op[c] = n / (sx[r] + sy[c] - n + EPS);
        }
        *(float4*)&out[(size_t)row * NROWS + colBase + tx * 4] = o;
    }
}

extern "C" void kernel_launch(void* const* d_in, const int* in_sizes, int n_in,
                              void* d_out, int out_size, void* d_ws, size_t ws_size,
                              hipStream_t stream) {
    const float* x = (const float*)d_in[0];
    const float* y = (const float*)d_in[1];
    float* out  = (float*)d_out;
    float* sums = (float*)d_ws;   // 2048 floats: Sx[1024] then Sy[1024]

    // Kernel A: 2048 rows, 4 rows (waves) per block
    rowsum_kernel<<<dim3(2048 / 4), dim3(256), 0, stream>>>(x, y, sums);

    // Kernel B: 16x16 blocks of 64x64 tiles
    ruzicka_kernel<<<dim3(NROWS / TN, NROWS / TM), dim3(256), 0, stream>>>(x, y, sums, out);
}